// Round 1
// baseline (17076.097 us; speedup 1.0000x reference)
//
#include <hip/hip_runtime.h>
#include <stdint.h>
#include <stddef.h>

// ---------------------------------------------------------------------------
// 3-layer LSTM (B=64,T=256,F=64,H=1024) + tanh projection, bf16 MFMA + fp32 acc.
// Phases: prep(cast/pack) -> [gemm_xg -> rec]x3 -> proj.
// rec: 64 persistent WGs, W_hh slice in registers, grid barrier per step.
// ---------------------------------------------------------------------------

#define B_ 64
#define T_ 256
#define F_ 64
#define H_ 1024
#define NG_ 4096          // 4*H
#define MR_ (B_*T_)       // 16384 rows, row index = t*64 + b

typedef __attribute__((ext_vector_type(8))) short short8;
typedef __attribute__((ext_vector_type(4))) short short4v;
typedef __attribute__((ext_vector_type(4))) float f32x4;
typedef unsigned short ushort_t;

__device__ __forceinline__ float bf2f(ushort_t u) {
  union { float f; unsigned int i; } v; v.i = ((unsigned int)u) << 16; return v.f;
}
__device__ __forceinline__ ushort_t f2bf(float f) {
  union { float f; unsigned int i; } v; v.f = f;
  unsigned int i = v.i;
  unsigned int r = (i + 0x7fffu + ((i >> 16) & 1u)) >> 16;  // RNE
  return (ushort_t)r;
}

__device__ __forceinline__ void gload_lds16(const void* g, void* l) {
  __builtin_amdgcn_global_load_lds(
      (const __attribute__((address_space(1))) void*)g,
      (__attribute__((address_space(3))) void*)l, 16, 0, 0);
}

__device__ __forceinline__ void load4x(const float* p, float* d) {
  float4 v = *(const float4*)p; d[0]=v.x; d[1]=v.y; d[2]=v.z; d[3]=v.w;
}
__device__ __forceinline__ void load4x(const ushort_t* p, float* d) {
  short4v v = *(const short4v*)p;
  d[0]=bf2f((ushort_t)v[0]); d[1]=bf2f((ushort_t)v[1]);
  d[2]=bf2f((ushort_t)v[2]); d[3]=bf2f((ushort_t)v[3]);
}

// ---------------------------------------------------------------------------
__global__ void init_sync_kernel(int* p) {
  if (threadIdx.x < 2) p[threadIdx.x] = 0;  // counter, flag
}

// ---------------------------------------------------------------------------
// prep: bf16 casts, hi/lo packing for layer-1 (X ~ N(0,1) needs >bf16), biases.
__global__ void prep_kernel(
    const float* __restrict__ X,
    const float* __restrict__ wih1, const float* __restrict__ whh1,
    const float* __restrict__ bih1, const float* __restrict__ bhh1,
    const float* __restrict__ wih2, const float* __restrict__ whh2,
    const float* __restrict__ bih2, const float* __restrict__ bhh2,
    const float* __restrict__ wih3, const float* __restrict__ whh3,
    const float* __restrict__ bih3, const float* __restrict__ bhh3,
    const float* __restrict__ wout,
    ushort_t* __restrict__ whh_bf, ushort_t* __restrict__ wih_bf,
    ushort_t* __restrict__ w1p, ushort_t* __restrict__ xp,
    ushort_t* __restrict__ wout_bf, float* __restrict__ bias)
{
  long long i0 = (long long)blockIdx.x * blockDim.x + threadIdx.x;
  long long stride = (long long)gridDim.x * blockDim.x;
  const long long NW = (long long)NG_ * H_;  // 4M

  for (long long i = i0; i < NW; i += stride) whh_bf[i]        = f2bf(whh1[i]);
  for (long long i = i0; i < NW; i += stride) whh_bf[NW + i]   = f2bf(whh2[i]);
  for (long long i = i0; i < NW; i += stride) whh_bf[2*NW + i] = f2bf(whh3[i]);
  for (long long i = i0; i < NW; i += stride) wih_bf[i]        = f2bf(wih2[i]);
  for (long long i = i0; i < NW; i += stride) wih_bf[NW + i]   = f2bf(wih3[i]);

  // W1 pack: row n of [4096][256] = [w_hi | w_hi | w_lo | w_lo]
  for (long long i = i0; i < (long long)NG_ * F_; i += stride) {
    int n = (int)(i / F_), f = (int)(i % F_);
    float wv = wih1[i];
    ushort_t hi = f2bf(wv);
    ushort_t lo = f2bf(wv - bf2f(hi));
    ushort_t* row = w1p + (long long)n * 256;
    row[f] = hi; row[64 + f] = hi; row[128 + f] = lo; row[192 + f] = lo;
  }
  // X pack: row (t*64+b) of [16384][256] = [x_hi | x_lo | x_hi | x_lo]
  for (long long i = i0; i < (long long)MR_ * F_; i += stride) {
    int b = (int)(i / (T_ * F_));
    int rem = (int)(i % (T_ * F_));
    int t = rem / F_, f = rem % F_;
    float xv = X[i];
    ushort_t hi = f2bf(xv);
    ushort_t lo = f2bf(xv - bf2f(hi));
    ushort_t* row = xp + ((long long)(t * B_ + b)) * 256;
    row[f] = hi; row[64 + f] = lo; row[128 + f] = hi; row[192 + f] = lo;
  }
  for (long long i = i0; i < (long long)F_ * H_; i += stride) wout_bf[i] = f2bf(wout[i]);
  for (long long i = i0; i < NG_; i += stride) {
    bias[i]          = bih1[i] + bhh1[i];
    bias[NG_ + i]    = bih2[i] + bhh2[i];
    bias[2*NG_ + i]  = bih3[i] + bhh3[i];
  }
}

// ---------------------------------------------------------------------------
// GEMM: C[M=16384, n] = A[M,K] * B[n,K]^T (+bias). 128x128 tile, BK=64,
// global_load_lds staging with XOR swizzle. MODE 0: store xg (XGT). MODE 1:
// tanh epilogue, scatter to [b][t][f] fp32.
template <int MODE, typename XGT>
__global__ __launch_bounds__(256) void gemm_kernel(
    const ushort_t* __restrict__ A, const ushort_t* __restrict__ Bm,
    const float* __restrict__ bias, void* __restrict__ out,
    int K, int Nreal)
{
  __shared__ ushort_t As[128 * 64];
  __shared__ ushort_t Bs[128 * 64];
  const int tid = threadIdx.x;
  const int w = tid >> 6, lane = tid & 63;
  const int mq = w & 1, nq = w >> 1;
  const int m0 = blockIdx.x * 128, n0 = blockIdx.y * 128;
  const int l8 = lane >> 3, l7 = lane & 7;
  const int kp = l7 ^ l8;  // fetch swizzle so LDS[r][p] holds kpart p^(r&7)

  f32x4 acc[4][4] = {};

  for (int k0 = 0; k0 < K; k0 += 64) {
    #pragma unroll
    for (int q = 0; q < 4; q++) {
      int c = w * 4 + q;                   // chunk 0..15, rows c*8..c*8+7
      int rowA = m0 + c * 8 + l8;
      gload_lds16(A + (size_t)rowA * K + k0 + kp * 8, (char*)As + c * 1024);
      int rowB = n0 + c * 8 + l8;
      if (rowB >= Nreal) rowB = Nreal - 1;
      gload_lds16(Bm + (size_t)rowB * K + k0 + kp * 8, (char*)Bs + c * 1024);
    }
    __syncthreads();
    #pragma unroll
    for (int ks = 0; ks < 2; ks++) {
      short8 af[4], bf[4];
      #pragma unroll
      for (int mt = 0; mt < 4; mt++) {
        int r = mq * 64 + mt * 16 + (lane & 15);
        int pos = (ks * 4 + (lane >> 4)) ^ (r & 7);
        af[mt] = *(const short8*)((const char*)As + r * 128 + pos * 16);
      }
      #pragma unroll
      for (int nt = 0; nt < 4; nt++) {
        int r = nq * 64 + nt * 16 + (lane & 15);
        int pos = (ks * 4 + (lane >> 4)) ^ (r & 7);
        bf[nt] = *(const short8*)((const char*)Bs + r * 128 + pos * 16);
      }
      #pragma unroll
      for (int mt = 0; mt < 4; mt++)
        #pragma unroll
        for (int nt = 0; nt < 4; nt++)
          acc[mt][nt] = __builtin_amdgcn_mfma_f32_16x16x32_bf16(
              af[mt], bf[nt], acc[mt][nt], 0, 0, 0);
    }
    __syncthreads();
  }

  #pragma unroll
  for (int mt = 0; mt < 4; mt++) {
    #pragma unroll
    for (int nt = 0; nt < 4; nt++) {
      #pragma unroll
      for (int r = 0; r < 4; r++) {
        int m = m0 + mq * 64 + mt * 16 + (lane >> 4) * 4 + r;
        int n = n0 + nq * 64 + nt * 16 + (lane & 15);
        float v = acc[mt][nt][r];
        if (MODE == 0) {
          v += bias[n];
          if (sizeof(XGT) == 4) ((float*)out)[(size_t)m * NG_ + n] = v;
          else                  ((ushort_t*)out)[(size_t)m * NG_ + n] = f2bf(v);
        } else {
          if (n < Nreal) {
            v = tanhf(v + bias[n]);
            int t = m >> 6, b = m & 63;           // m = t*64 + b
            ((float*)out)[((size_t)(b * T_ + t)) * F_ + n] = v;
          }
        }
      }
    }
  }
}

// ---------------------------------------------------------------------------
// Recurrence: 64 WGs x 256 threads (4 waves, 2x2 M/N split). Each WG owns
// j-slice jWG..jWG+15 -> gate rows {g*1024 + jWG + jl}. W_hh B-frags persist
// in registers across all 256 steps. Grid barrier (monotonic counter) per step.
template <typename XGT>
__global__ __launch_bounds__(256, 1) void rec_kernel(
    const XGT* __restrict__ xg, const ushort_t* __restrict__ whh,
    ushort_t* __restrict__ hseq,
    ushort_t* __restrict__ hping, ushort_t* __restrict__ hpong,
    int* cnt, int* flag, int step_base)
{
  const int wg = blockIdx.x;           // 0..63
  const int tid = threadIdx.x;
  const int w = tid >> 6, lane = tid & 63;
  const int mq = w & 1, nq = w >> 1;
  const int jWG = wg * 16;
  __shared__ float PG[64 * 65];        // pre-gates [m][sc], stride 65 (banks)

  // persistent B fragments: wave covers 32 slice-cols (sc = g*16 + jl)
  short8 bfr[2][32];
  #pragma unroll
  for (int nt = 0; nt < 2; nt++) {
    int sc = nq * 32 + nt * 16 + (lane & 15);
    int n = (sc >> 4) * H_ + jWG + (sc & 15);
    const ushort_t* wrow = whh + (size_t)n * H_ + (lane >> 4) * 8;
    #pragma unroll
    for (int ks = 0; ks < 32; ks++)
      bfr[nt][ks] = *(const short8*)(wrow + ks * 32);
  }

  const int em = tid & 63;             // elementwise: batch row
  const int jg = tid >> 6;             // j group (4 j's)
  float cst[4] = {0.f, 0.f, 0.f, 0.f}; // fp32 cell state, persistent

  const int a0off = (mq * 32 + (lane & 15)) * H_ + (lane >> 4) * 8;
  const int a1off = a0off + 16 * H_;

  for (int t = 0; t < T_; t++) {
    const ushort_t* hin = (t & 1) ? hpong : hping;
    ushort_t*       hout = (t & 1) ? hping : hpong;

    // prefetch xg for this (t, em, jWG+jg*4..+3)
    const XGT* xrow = xg + ((size_t)(t * B_ + em)) * NG_ + jWG + jg * 4;
    float xv[4][4];
    #pragma unroll
    for (int g = 0; g < 4; g++) load4x(xrow + g * H_, xv[g]);

    f32x4 acc[2][2] = {};
    if (t > 0) {  // t==0: h = 0, gates = xg only (also avoids zero-init of h)
      #pragma unroll
      for (int ks = 0; ks < 32; ks++) {
        short8 a0 = *(const short8*)(hin + a0off + ks * 32);
        short8 a1 = *(const short8*)(hin + a1off + ks * 32);
        acc[0][0] = __builtin_amdgcn_mfma_f32_16x16x32_bf16(a0, bfr[0][ks], acc[0][0], 0,0,0);
        acc[1][0] = __builtin_amdgcn_mfma_f32_16x16x32_bf16(a1, bfr[0][ks], acc[1][0], 0,0,0);
        acc[0][1] = __builtin_amdgcn_mfma_f32_16x16x32_bf16(a0, bfr[1][ks], acc[0][1], 0,0,0);
        acc[1][1] = __builtin_amdgcn_mfma_f32_16x16x32_bf16(a1, bfr[1][ks], acc[1][1], 0,0,0);
      }
    }

    // scatter pre-gates (MFMA C layout) to LDS for gate regrouping
    #pragma unroll
    for (int mt = 0; mt < 2; mt++)
      #pragma unroll
      for (int nt = 0; nt < 2; nt++)
        #pragma unroll
        for (int r = 0; r < 4; r++) {
          int m = mq * 32 + mt * 16 + (lane >> 4) * 4 + r;
          int sc = nq * 32 + nt * 16 + (lane & 15);
          PG[m * 65 + sc] = acc[mt][nt][r];
        }
    __syncthreads();

    // elementwise LSTM cell: thread owns (em, jl = jg*4+u)
    short4v hb;
    #pragma unroll
    for (int u = 0; u < 4; u++) {
      int jl = jg * 4 + u;
      float pi = PG[em * 65 + jl]      + xv[0][u];
      float pf = PG[em * 65 + 16 + jl] + xv[1][u];
      float pg = PG[em * 65 + 32 + jl] + xv[2][u];
      float po = PG[em * 65 + 48 + jl] + xv[3][u];
      float ii = 1.f / (1.f + __expf(-pi));
      float ff = 1.f / (1.f + __expf(-pf));
      float gg = tanhf(pg);
      float oo = 1.f / (1.f + __expf(-po));
      cst[u] = ff * cst[u] + ii * gg;
      float hv = oo * tanhf(cst[u]);
      hb[u] = (short)f2bf(hv);
    }
    *(short4v*)(hout + em * H_ + jWG + jg * 4) = hb;
    *(short4v*)(hseq + ((size_t)(t * B_ + em)) * H_ + jWG + jg * 4) = hb;

    // grid barrier (device scope; monotonic across the 3 layer launches)
    __syncthreads();
    if (tid == 0) {
      int tgt = step_base + t + 1;
      int old = __hip_atomic_fetch_add(cnt, 1, __ATOMIC_ACQ_REL, __HIP_MEMORY_SCOPE_AGENT);
      if (old == 64 * tgt - 1) {
        __hip_atomic_store(flag, tgt, __ATOMIC_RELEASE, __HIP_MEMORY_SCOPE_AGENT);
      } else {
        while (__hip_atomic_load(flag, __ATOMIC_RELAXED, __HIP_MEMORY_SCOPE_AGENT) < tgt)
          __builtin_amdgcn_s_sleep(1);
      }
      __threadfence();
    }
    __syncthreads();
  }
}

// ---------------------------------------------------------------------------
extern "C" void kernel_launch(void* const* d_in, const int* in_sizes, int n_in,
                              void* d_out, int out_size, void* d_ws, size_t ws_size,
                              hipStream_t stream)
{
  (void)in_sizes; (void)n_in; (void)out_size;
  const float* X    = (const float*)d_in[0];
  const float* wih1 = (const float*)d_in[1];
  const float* whh1 = (const float*)d_in[2];
  const float* bih1 = (const float*)d_in[3];
  const float* bhh1 = (const float*)d_in[4];
  const float* wih2 = (const float*)d_in[5];
  const float* whh2 = (const float*)d_in[6];
  const float* bih2 = (const float*)d_in[7];
  const float* bhh2 = (const float*)d_in[8];
  const float* wih3 = (const float*)d_in[9];
  const float* whh3 = (const float*)d_in[10];
  const float* bih3 = (const float*)d_in[11];
  const float* bhh3 = (const float*)d_in[12];
  const float* wout = (const float*)d_in[13];
  const float* bout = (const float*)d_in[14];

  const size_t NW = (size_t)NG_ * H_;           // 4M elems
  const size_t sz_seq  = (size_t)MR_ * H_ * 2;  // bf16 h sequence
  const size_t sz_whh  = 3 * NW * 2;
  const size_t sz_wih  = 2 * NW * 2;
  const size_t sz_w1p  = (size_t)NG_ * 256 * 2;
  const size_t sz_xp   = (size_t)MR_ * 256 * 2;
  const size_t sz_wout = (size_t)F_ * H_ * 2;
  const size_t sz_bias = 3 * (size_t)NG_ * 4;
  const size_t sz_h    = (size_t)B_ * H_ * 2;
  const size_t fixed = 2*sz_seq + sz_whh + sz_wih + sz_w1p + sz_xp + sz_wout
                     + sz_bias + 2*sz_h + 8192;
  const size_t xg_f32 = (size_t)MR_ * NG_ * 4;
  const bool xg32 = ws_size >= fixed + xg_f32 + (1u << 20);

  char* ws = (char*)d_ws;
  size_t off = 0;
  auto alloc = [&](size_t bytes) -> void* {
    void* p = ws + off; off += (bytes + 255) & ~(size_t)255; return p;
  };
  void*     xg      = alloc(xg32 ? xg_f32 : (size_t)MR_ * NG_ * 2);
  ushort_t* seqA    = (ushort_t*)alloc(sz_seq);
  ushort_t* seqB    = (ushort_t*)alloc(sz_seq);
  ushort_t* whh_bf  = (ushort_t*)alloc(sz_whh);
  ushort_t* wih_bf  = (ushort_t*)alloc(sz_wih);
  ushort_t* w1p     = (ushort_t*)alloc(sz_w1p);
  ushort_t* xp      = (ushort_t*)alloc(sz_xp);
  ushort_t* wout_bf = (ushort_t*)alloc(sz_wout);
  float*    bias    = (float*)alloc(sz_bias);
  ushort_t* hping   = (ushort_t*)alloc(sz_h);
  ushort_t* hpong   = (ushort_t*)alloc(sz_h);
  int*      sync    = (int*)alloc(256);   // [0]=counter, [1]=flag

  init_sync_kernel<<<1, 64, 0, stream>>>(sync);
  prep_kernel<<<1024, 256, 0, stream>>>(
      X, wih1, whh1, bih1, bhh1, wih2, whh2, bih2, bhh2,
      wih3, whh3, bih3, bhh3, wout,
      whh_bf, wih_bf, w1p, xp, wout_bf, bias);

  dim3 ggrid(128, 32), gblk(256);
  if (xg32) {
    gemm_kernel<0, float><<<ggrid, gblk, 0, stream>>>(xp, w1p, bias, xg, 256, NG_);
    rec_kernel<float><<<64, 256, 0, stream>>>((const float*)xg, whh_bf, seqA,
                                              hping, hpong, sync, sync + 1, 0);
    gemm_kernel<0, float><<<ggrid, gblk, 0, stream>>>(seqA, wih_bf, bias + NG_, xg, 1024, NG_);
    rec_kernel<float><<<64, 256, 0, stream>>>((const float*)xg, whh_bf + NW, seqB,
                                              hping, hpong, sync, sync + 1, 256);
    gemm_kernel<0, float><<<ggrid, gblk, 0, stream>>>(seqB, wih_bf + NW, bias + 2*NG_, xg, 1024, NG_);
    rec_kernel<float><<<64, 256, 0, stream>>>((const float*)xg, whh_bf + 2*NW, seqA,
                                              hping, hpong, sync, sync + 1, 512);
  } else {
    gemm_kernel<0, ushort_t><<<ggrid, gblk, 0, stream>>>(xp, w1p, bias, xg, 256, NG_);
    rec_kernel<ushort_t><<<64, 256, 0, stream>>>((const ushort_t*)xg, whh_bf, seqA,
                                                 hping, hpong, sync, sync + 1, 0);
    gemm_kernel<0, ushort_t><<<ggrid, gblk, 0, stream>>>(seqA, wih_bf, bias + NG_, xg, 1024, NG_);
    rec_kernel<ushort_t><<<64, 256, 0, stream>>>((const ushort_t*)xg, whh_bf + NW, seqB,
                                                 hping, hpong, sync, sync + 1, 256);
    gemm_kernel<0, ushort_t><<<ggrid, gblk, 0, stream>>>(seqB, wih_bf + NW, bias + 2*NG_, xg, 1024, NG_);
    rec_kernel<ushort_t><<<64, 256, 0, stream>>>((const ushort_t*)xg, whh_bf + 2*NW, seqA,
                                                 hping, hpong, sync, sync + 1, 512);
  }
  gemm_kernel<1, float><<<dim3(128, 1), gblk, 0, stream>>>(
      seqA, wout_bf, bout, d_out, 1024, F_);
}

// Round 2
// 16758.740 us; speedup vs baseline: 1.0189x; 1.0189x over previous
//
#include <hip/hip_runtime.h>
#include <stdint.h>
#include <stddef.h>

// ---------------------------------------------------------------------------
// 3-layer LSTM (B=64,T=256,F=64,H=1024) + tanh projection, bf16 MFMA + fp32 acc.
// Phases: prep(cast/pack) -> [gemm_xg -> rec]x3 -> proj.
// rec: 64 persistent WGs, 4-way K-split, W_hh in regs/AGPRs, flag-array
// barrier with agent-scope (sc1) accesses only — no L2 writeback/invalidate.
// ---------------------------------------------------------------------------

#define B_ 64
#define T_ 256
#define F_ 64
#define H_ 1024
#define NG_ 4096          // 4*H
#define MR_ (B_*T_)       // 16384 rows, row index = t*64 + b

typedef __attribute__((ext_vector_type(8))) short short8;
typedef __attribute__((ext_vector_type(4))) short short4v;
typedef __attribute__((ext_vector_type(4))) float f32x4;
typedef unsigned short ushort_t;
typedef unsigned long long ull;

__device__ __forceinline__ float bf2f(ushort_t u) {
  union { float f; unsigned int i; } v; v.i = ((unsigned int)u) << 16; return v.f;
}
__device__ __forceinline__ ushort_t f2bf(float f) {
  union { float f; unsigned int i; } v; v.f = f;
  unsigned int i = v.i;
  unsigned int r = (i + 0x7fffu + ((i >> 16) & 1u)) >> 16;  // RNE
  return (ushort_t)r;
}

__device__ __forceinline__ void gload_lds16(const void* g, void* l) {
  __builtin_amdgcn_global_load_lds(
      (const __attribute__((address_space(1))) void*)g,
      (__attribute__((address_space(3))) void*)l, 16, 0, 0);
}

__device__ __forceinline__ void load4x(const float* p, float* d) {
  float4 v = *(const float4*)p; d[0]=v.x; d[1]=v.y; d[2]=v.z; d[3]=v.w;
}
__device__ __forceinline__ void load4x(const ushort_t* p, float* d) {
  short4v v = *(const short4v*)p;
  d[0]=bf2f((ushort_t)v[0]); d[1]=bf2f((ushort_t)v[1]);
  d[2]=bf2f((ushort_t)v[2]); d[3]=bf2f((ushort_t)v[3]);
}

__device__ __forceinline__ float fsig(float x)  { return 1.f / (1.f + __expf(-x)); }
__device__ __forceinline__ float ftanh(float x) { return 1.f - 2.f / (1.f + __expf(2.f * x)); }

// ---------------------------------------------------------------------------
__global__ void init_sync_kernel(int* p) {
  p[threadIdx.x] = 0;  // 64 flag slots
}

// ---------------------------------------------------------------------------
// prep: bf16 casts, hi/lo packing for layer-1 (X ~ N(0,1) needs >bf16), biases.
__global__ void prep_kernel(
    const float* __restrict__ X,
    const float* __restrict__ wih1, const float* __restrict__ whh1,
    const float* __restrict__ bih1, const float* __restrict__ bhh1,
    const float* __restrict__ wih2, const float* __restrict__ whh2,
    const float* __restrict__ bih2, const float* __restrict__ bhh2,
    const float* __restrict__ wih3, const float* __restrict__ whh3,
    const float* __restrict__ bih3, const float* __restrict__ bhh3,
    const float* __restrict__ wout,
    ushort_t* __restrict__ whh_bf, ushort_t* __restrict__ wih_bf,
    ushort_t* __restrict__ w1p, ushort_t* __restrict__ xp,
    ushort_t* __restrict__ wout_bf, float* __restrict__ bias)
{
  long long i0 = (long long)blockIdx.x * blockDim.x + threadIdx.x;
  long long stride = (long long)gridDim.x * blockDim.x;
  const long long NW = (long long)NG_ * H_;  // 4M

  for (long long i = i0; i < NW; i += stride) whh_bf[i]        = f2bf(whh1[i]);
  for (long long i = i0; i < NW; i += stride) whh_bf[NW + i]   = f2bf(whh2[i]);
  for (long long i = i0; i < NW; i += stride) whh_bf[2*NW + i] = f2bf(whh3[i]);
  for (long long i = i0; i < NW; i += stride) wih_bf[i]        = f2bf(wih2[i]);
  for (long long i = i0; i < NW; i += stride) wih_bf[NW + i]   = f2bf(wih3[i]);

  // W1 pack: row n of [4096][256] = [w_hi | w_hi | w_lo | w_lo]
  for (long long i = i0; i < (long long)NG_ * F_; i += stride) {
    int n = (int)(i / F_), f = (int)(i % F_);
    float wv = wih1[i];
    ushort_t hi = f2bf(wv);
    ushort_t lo = f2bf(wv - bf2f(hi));
    ushort_t* row = w1p + (long long)n * 256;
    row[f] = hi; row[64 + f] = hi; row[128 + f] = lo; row[192 + f] = lo;
  }
  // X pack: row (t*64+b) of [16384][256] = [x_hi | x_lo | x_hi | x_lo]
  for (long long i = i0; i < (long long)MR_ * F_; i += stride) {
    int b = (int)(i / (T_ * F_));
    int rem = (int)(i % (T_ * F_));
    int t = rem / F_, f = rem % F_;
    float xv = X[i];
    ushort_t hi = f2bf(xv);
    ushort_t lo = f2bf(xv - bf2f(hi));
    ushort_t* row = xp + ((long long)(t * B_ + b)) * 256;
    row[f] = hi; row[64 + f] = lo; row[128 + f] = hi; row[192 + f] = lo;
  }
  for (long long i = i0; i < (long long)F_ * H_; i += stride) wout_bf[i] = f2bf(wout[i]);
  for (long long i = i0; i < NG_; i += stride) {
    bias[i]          = bih1[i] + bhh1[i];
    bias[NG_ + i]    = bih2[i] + bhh2[i];
    bias[2*NG_ + i]  = bih3[i] + bhh3[i];
  }
}

// ---------------------------------------------------------------------------
// GEMM: C[M=16384, n] = A[M,K] * B[n,K]^T (+bias). 128x128 tile, BK=64,
// global_load_lds staging with XOR swizzle. MODE 0: store xg (XGT). MODE 1:
// tanh epilogue, scatter to [b][t][f] fp32.
template <int MODE, typename XGT>
__global__ __launch_bounds__(256) void gemm_kernel(
    const ushort_t* __restrict__ A, const ushort_t* __restrict__ Bm,
    const float* __restrict__ bias, void* __restrict__ out,
    int K, int Nreal)
{
  __shared__ ushort_t As[128 * 64];
  __shared__ ushort_t Bs[128 * 64];
  const int tid = threadIdx.x;
  const int w = tid >> 6, lane = tid & 63;
  const int mq = w & 1, nq = w >> 1;
  const int m0 = blockIdx.x * 128, n0 = blockIdx.y * 128;
  const int l8 = lane >> 3, l7 = lane & 7;
  const int kp = l7 ^ l8;  // fetch swizzle so LDS[r][p] holds kpart p^(r&7)

  f32x4 acc[4][4] = {};

  for (int k0 = 0; k0 < K; k0 += 64) {
    #pragma unroll
    for (int q = 0; q < 4; q++) {
      int c = w * 4 + q;                   // chunk 0..15, rows c*8..c*8+7
      int rowA = m0 + c * 8 + l8;
      gload_lds16(A + (size_t)rowA * K + k0 + kp * 8, (char*)As + c * 1024);
      int rowB = n0 + c * 8 + l8;
      if (rowB >= Nreal) rowB = Nreal - 1;
      gload_lds16(Bm + (size_t)rowB * K + k0 + kp * 8, (char*)Bs + c * 1024);
    }
    __syncthreads();
    #pragma unroll
    for (int ks = 0; ks < 2; ks++) {
      short8 af[4], bf[4];
      #pragma unroll
      for (int mt = 0; mt < 4; mt++) {
        int r = mq * 64 + mt * 16 + (lane & 15);
        int pos = (ks * 4 + (lane >> 4)) ^ (r & 7);
        af[mt] = *(const short8*)((const char*)As + r * 128 + pos * 16);
      }
      #pragma unroll
      for (int nt = 0; nt < 4; nt++) {
        int r = nq * 64 + nt * 16 + (lane & 15);
        int pos = (ks * 4 + (lane >> 4)) ^ (r & 7);
        bf[nt] = *(const short8*)((const char*)Bs + r * 128 + pos * 16);
      }
      #pragma unroll
      for (int mt = 0; mt < 4; mt++)
        #pragma unroll
        for (int nt = 0; nt < 4; nt++)
          acc[mt][nt] = __builtin_amdgcn_mfma_f32_16x16x32_bf16(
              af[mt], bf[nt], acc[mt][nt], 0, 0, 0);
    }
    __syncthreads();
  }

  #pragma unroll
  for (int mt = 0; mt < 4; mt++) {
    #pragma unroll
    for (int nt = 0; nt < 4; nt++) {
      #pragma unroll
      for (int r = 0; r < 4; r++) {
        int m = m0 + mq * 64 + mt * 16 + (lane >> 4) * 4 + r;
        int n = n0 + nq * 64 + nt * 16 + (lane & 15);
        float v = acc[mt][nt][r];
        if (MODE == 0) {
          v += bias[n];
          if (sizeof(XGT) == 4) ((float*)out)[(size_t)m * NG_ + n] = v;
          else                  ((ushort_t*)out)[(size_t)m * NG_ + n] = f2bf(v);
        } else {
          if (n < Nreal) {
            v = tanhf(v + bias[n]);
            int t = m >> 6, b = m & 63;           // m = t*64 + b
            ((float*)out)[((size_t)(b * T_ + t)) * F_ + n] = v;
          }
        }
      }
    }
  }
}

// ---------------------------------------------------------------------------
// Recurrence: 64 WGs x 256 threads (4 waves = 4-way K-split, 256 K each).
// Each WG owns j-slice jWG..jWG+15 -> gate rows {g*1024 + jWG + jl}.
// W_hh B-frags (128 VGPR/lane) persist in registers across all 256 steps.
// Cross-WG h via agent-scope relaxed atomics (sc1, LLC-coherent, no L2
// maintenance). Barrier: 64-slot monotonic flag array + ballot poll.
template <typename XGT>
__global__ __launch_bounds__(256, 1) void rec_kernel(
    const XGT* __restrict__ xg, const ushort_t* __restrict__ whh,
    ushort_t* __restrict__ hseq,
    ushort_t* __restrict__ hping, ushort_t* __restrict__ hpong,
    int* __restrict__ slots, int step_base)
{
  const int wg = blockIdx.x;           // 0..63
  const int tid = threadIdx.x;
  const int kq = tid >> 6, lane = tid & 63;
  const int l15 = lane & 15, l4 = lane >> 4;
  const int jWG = wg * 16;
  __shared__ float PG[2][64][68];      // partial pre-gates, 2 reduce buffers

  // persistent B fragments: frag (nt=gate, ks): n = nt*1024+jWG+l15,
  // k = kq*256 + ks*32 + l4*8.  4*8 short8 = 128 VGPRs/lane.
  short8 bfr[4][8];
  #pragma unroll
  for (int nt = 0; nt < 4; nt++)
    #pragma unroll
    for (int ks = 0; ks < 8; ks++)
      bfr[nt][ks] = *(const short8*)(
          whh + ((size_t)(nt * H_ + jWG + l15)) * H_ + kq * 256 + ks * 32 + l4 * 8);

  const int em = lane;                 // elementwise: batch row (tid&63)
  float cst[4] = {0.f, 0.f, 0.f, 0.f}; // fp32 cell state, persistent
  const size_t abase = (size_t)l15 * H_ + kq * 256 + l4 * 8;

  for (int t = 0; t < T_; t++) {
    const ushort_t* hin  = (t & 1) ? hpong : hping;
    ushort_t*       hout = (t & 1) ? hping : hpong;

    // xg prefetch (plain loads, independent of the barrier)
    const XGT* xrow = xg + ((size_t)(t * B_ + em)) * NG_ + jWG + kq * 4;
    f32x4 xv[4];
    #pragma unroll
    for (int g = 0; g < 4; g++) {
      float tmp[4]; load4x(xrow + g * H_, tmp);
      xv[g][0]=tmp[0]; xv[g][1]=tmp[1]; xv[g][2]=tmp[2]; xv[g][3]=tmp[3];
    }

    f32x4 acc[4][4] = {};
    if (t > 0) {
      // wait for all WGs to have finished step t-1 (slot >= step_base+t)
      int tgt = step_base + t;
      int v = __hip_atomic_load(&slots[lane], __ATOMIC_RELAXED, __HIP_MEMORY_SCOPE_AGENT);
      while (__ballot(v >= tgt) != ~0ull) {
        __builtin_amdgcn_s_sleep(2);
        v = __hip_atomic_load(&slots[lane], __ATOMIC_RELAXED, __HIP_MEMORY_SCOPE_AGENT);
      }
      // A (= h[t-1]) loads: agent-scope 8B atomics (sc1 -> LLC, bypass L2)
      ull au[4][8][2];
      #pragma unroll
      for (int mt = 0; mt < 4; mt++)
        #pragma unroll
        for (int ks = 0; ks < 8; ks++) {
          const ull* p = (const ull*)(hin + abase + (size_t)mt * 16 * H_ + ks * 32);
          au[mt][ks][0] = __hip_atomic_load(p,     __ATOMIC_RELAXED, __HIP_MEMORY_SCOPE_AGENT);
          au[mt][ks][1] = __hip_atomic_load(p + 1, __ATOMIC_RELAXED, __HIP_MEMORY_SCOPE_AGENT);
        }
      #pragma unroll
      for (int ks = 0; ks < 8; ks++)
        #pragma unroll
        for (int mt = 0; mt < 4; mt++) {
          union { ull u[2]; short8 s; } a;
          a.u[0] = au[mt][ks][0]; a.u[1] = au[mt][ks][1];
          #pragma unroll
          for (int nt = 0; nt < 4; nt++)
            acc[mt][nt] = __builtin_amdgcn_mfma_f32_16x16x32_bf16(
                a.s, bfr[nt][ks], acc[mt][nt], 0, 0, 0);
        }
    }

    // K-partial reduction through LDS: waves 0,1 write; waves 2,3 ds-add.
    if (kq < 2) {
      #pragma unroll
      for (int mt = 0; mt < 4; mt++)
        #pragma unroll
        for (int nt = 0; nt < 4; nt++)
          #pragma unroll
          for (int r = 0; r < 4; r++)
            PG[kq][mt * 16 + l4 * 4 + r][nt * 16 + l15] = acc[mt][nt][r];
    }
    __syncthreads();
    if (kq >= 2) {
      #pragma unroll
      for (int mt = 0; mt < 4; mt++)
        #pragma unroll
        for (int nt = 0; nt < 4; nt++)
          #pragma unroll
          for (int r = 0; r < 4; r++)
            atomicAdd(&PG[kq - 2][mt * 16 + l4 * 4 + r][nt * 16 + l15], acc[mt][nt][r]);
    }
    __syncthreads();

    // elementwise LSTM cell: thread owns (em, jl = kq*4+u)
    f32x4 p[4];
    #pragma unroll
    for (int g = 0; g < 4; g++) {
      f32x4 p0 = *(const f32x4*)&PG[0][em][g * 16 + kq * 4];
      f32x4 p1 = *(const f32x4*)&PG[1][em][g * 16 + kq * 4];
      p[g] = p0 + p1 + xv[g];
    }
    short4v hb;
    #pragma unroll
    for (int u = 0; u < 4; u++) {
      float ii = fsig(p[0][u]);
      float ff = fsig(p[1][u]);
      float gg = ftanh(p[2][u]);
      float oo = fsig(p[3][u]);
      cst[u] = ff * cst[u] + ii * gg;
      hb[u] = (short)f2bf(oo * ftanh(cst[u]));
    }
    union { short4v s; ull u; } hh; hh.s = hb;
    const size_t hidx = (size_t)em * H_ + jWG + kq * 4;
    __hip_atomic_store((ull*)(hout + hidx), hh.u,
                       __ATOMIC_RELAXED, __HIP_MEMORY_SCOPE_AGENT);
    __builtin_nontemporal_store(
        hh.u, (ull*)(hseq + ((size_t)(t * B_ + em)) * H_ + jWG + kq * 4));

    // publish: drain own stores, WG-join, then one flag store per WG
    __builtin_amdgcn_s_waitcnt(0);
    __syncthreads();
    if (tid == 0)
      __hip_atomic_store(&slots[wg], step_base + t + 1,
                         __ATOMIC_RELAXED, __HIP_MEMORY_SCOPE_AGENT);
  }
}

// ---------------------------------------------------------------------------
extern "C" void kernel_launch(void* const* d_in, const int* in_sizes, int n_in,
                              void* d_out, int out_size, void* d_ws, size_t ws_size,
                              hipStream_t stream)
{
  (void)in_sizes; (void)n_in; (void)out_size;
  const float* X    = (const float*)d_in[0];
  const float* wih1 = (const float*)d_in[1];
  const float* whh1 = (const float*)d_in[2];
  const float* bih1 = (const float*)d_in[3];
  const float* bhh1 = (const float*)d_in[4];
  const float* wih2 = (const float*)d_in[5];
  const float* whh2 = (const float*)d_in[6];
  const float* bih2 = (const float*)d_in[7];
  const float* bhh2 = (const float*)d_in[8];
  const float* wih3 = (const float*)d_in[9];
  const float* whh3 = (const float*)d_in[10];
  const float* bih3 = (const float*)d_in[11];
  const float* bhh3 = (const float*)d_in[12];
  const float* wout = (const float*)d_in[13];
  const float* bout = (const float*)d_in[14];

  const size_t NW = (size_t)NG_ * H_;           // 4M elems
  const size_t sz_seq  = (size_t)MR_ * H_ * 2;  // bf16 h sequence
  const size_t sz_whh  = 3 * NW * 2;
  const size_t sz_wih  = 2 * NW * 2;
  const size_t sz_w1p  = (size_t)NG_ * 256 * 2;
  const size_t sz_xp   = (size_t)MR_ * 256 * 2;
  const size_t sz_wout = (size_t)F_ * H_ * 2;
  const size_t sz_bias = 3 * (size_t)NG_ * 4;
  const size_t sz_h    = (size_t)B_ * H_ * 2;
  const size_t fixed = 2*sz_seq + sz_whh + sz_wih + sz_w1p + sz_xp + sz_wout
                     + sz_bias + 2*sz_h + 8192;
  const size_t xg_f32 = (size_t)MR_ * NG_ * 4;
  const bool xg32 = ws_size >= fixed + xg_f32 + (1u << 20);

  char* ws = (char*)d_ws;
  size_t off = 0;
  auto alloc = [&](size_t bytes) -> void* {
    void* p = ws + off; off += (bytes + 255) & ~(size_t)255; return p;
  };
  void*     xg      = alloc(xg32 ? xg_f32 : (size_t)MR_ * NG_ * 2);
  ushort_t* seqA    = (ushort_t*)alloc(sz_seq);
  ushort_t* seqB    = (ushort_t*)alloc(sz_seq);
  ushort_t* whh_bf  = (ushort_t*)alloc(sz_whh);
  ushort_t* wih_bf  = (ushort_t*)alloc(sz_wih);
  ushort_t* w1p     = (ushort_t*)alloc(sz_w1p);
  ushort_t* xp      = (ushort_t*)alloc(sz_xp);
  ushort_t* wout_bf = (ushort_t*)alloc(sz_wout);
  float*    bias    = (float*)alloc(sz_bias);
  ushort_t* hping   = (ushort_t*)alloc(sz_h);
  ushort_t* hpong   = (ushort_t*)alloc(sz_h);
  int*      slots   = (int*)alloc(256);   // 64 per-WG flag slots

  init_sync_kernel<<<1, 64, 0, stream>>>(slots);
  prep_kernel<<<1024, 256, 0, stream>>>(
      X, wih1, whh1, bih1, bhh1, wih2, whh2, bih2, bhh2,
      wih3, whh3, bih3, bhh3, wout,
      whh_bf, wih_bf, w1p, xp, wout_bf, bias);

  dim3 ggrid(128, 32), gblk(256);
  if (xg32) {
    gemm_kernel<0, float><<<ggrid, gblk, 0, stream>>>(xp, w1p, bias, xg, 256, NG_);
    rec_kernel<float><<<64, 256, 0, stream>>>((const float*)xg, whh_bf, seqA,
                                              hping, hpong, slots, 0);
    gemm_kernel<0, float><<<ggrid, gblk, 0, stream>>>(seqA, wih_bf, bias + NG_, xg, 1024, NG_);
    rec_kernel<float><<<64, 256, 0, stream>>>((const float*)xg, whh_bf + NW, seqB,
                                              hping, hpong, slots, 256);
    gemm_kernel<0, float><<<ggrid, gblk, 0, stream>>>(seqB, wih_bf + NW, bias + 2*NG_, xg, 1024, NG_);
    rec_kernel<float><<<64, 256, 0, stream>>>((const float*)xg, whh_bf + 2*NW, seqA,
                                              hping, hpong, slots, 512);
  } else {
    gemm_kernel<0, ushort_t><<<ggrid, gblk, 0, stream>>>(xp, w1p, bias, xg, 256, NG_);
    rec_kernel<ushort_t><<<64, 256, 0, stream>>>((const ushort_t*)xg, whh_bf, seqA,
                                                 hping, hpong, slots, 0);
    gemm_kernel<0, ushort_t><<<ggrid, gblk, 0, stream>>>(seqA, wih_bf, bias + NG_, xg, 1024, NG_);
    rec_kernel<ushort_t><<<64, 256, 0, stream>>>((const ushort_t*)xg, whh_bf + NW, seqB,
                                                 hping, hpong, slots, 256);
    gemm_kernel<0, ushort_t><<<ggrid, gblk, 0, stream>>>(seqB, wih_bf + NW, bias + 2*NG_, xg, 1024, NG_);
    rec_kernel<ushort_t><<<64, 256, 0, stream>>>((const ushort_t*)xg, whh_bf + 2*NW, seqA,
                                                 hping, hpong, slots, 512);
  }
  gemm_kernel<1, float><<<dim3(128, 1), gblk, 0, stream>>>(
      seqA, wout_bf, bout, d_out, 1024, F_);
}